// Round 3
// baseline (99.872 us; speedup 1.0000x reference)
//
#include <hip/hip_runtime.h>

// O[b,q,e] = (Q·K^T)/(sqrt(128)*qk_sf) @ V  ==  Q @ (K^T V) * s   (no softmax)
// B=8, S=2048, D=128 fp32.
// K1: P[blk][e=128][d=128] bf16 partial of V^T K over 32 k-rows (grid 512)
// K2: Tt[b][e][d] = s * sum_{kc<64} P  (bf16, scale folded; grid 256)
// K3: O = Q @ T via mfma_f32_16x16x32_bf16 (B-frag reads Tt[e][d] contiguously)

#define BATCH 8
#define SEQ 2048
#define DIM 128

typedef __attribute__((ext_vector_type(8))) short short8;
typedef __attribute__((ext_vector_type(4))) float f32x4;

__device__ __forceinline__ unsigned int f2bf(float f) {
    unsigned int u = __float_as_uint(f);
    u += 0x7fffu + ((u >> 16) & 1u);   // RNE
    return u >> 16;
}

// ---------------- K1: partial V^T K, 8x8 register tile ----------------------
// blockIdx = b*64 + kc ; chunk = 32 k-rows ; out P[blk] = 128e x 128d bf16
__global__ __launch_bounds__(256) void vtk_partial(const float* __restrict__ K,
                                                   const float* __restrict__ V,
                                                   unsigned short* __restrict__ P) {
    __shared__ float Kc[32 * 128];   // 16 KB
    __shared__ float Vc[32 * 128];   // 16 KB
    const int blk = blockIdx.x;
    const int b   = blk >> 6;
    const int kc  = blk & 63;
    const int tid = threadIdx.x;

    const float4* Kg = (const float4*)(K + ((size_t)b * SEQ + kc * 32) * DIM);
    const float4* Vg = (const float4*)(V + ((size_t)b * SEQ + kc * 32) * DIM);
    #pragma unroll
    for (int i = 0; i < 4; i++) {                 // 1024 float4 each
        int idx = tid + i * 256;
        ((float4*)Kc)[idx] = Kg[idx];
        ((float4*)Vc)[idx] = Vg[idx];
    }
    __syncthreads();

    const int td = tid & 15;    // d-octet: d = td*8..td*8+7
    const int te = tid >> 4;    // e-octet: e = te*8..te*8+7

    float acc[8][8];
    #pragma unroll
    for (int i = 0; i < 8; i++)
        #pragma unroll
        for (int j = 0; j < 8; j++) acc[i][j] = 0.0f;

    #pragma unroll 4
    for (int k = 0; k < 32; k++) {
        // broadcast/2-way LDS reads: free
        const float4 k0 = *(const float4*)&Kc[k * 128 + td * 8];
        const float4 k1 = *(const float4*)&Kc[k * 128 + td * 8 + 4];
        const float4 v0 = *(const float4*)&Vc[k * 128 + te * 8];
        const float4 v1 = *(const float4*)&Vc[k * 128 + te * 8 + 4];
        const float kd[8] = {k0.x, k0.y, k0.z, k0.w, k1.x, k1.y, k1.z, k1.w};
        const float ve[8] = {v0.x, v0.y, v0.z, v0.w, v1.x, v1.y, v1.z, v1.w};
        #pragma unroll
        for (int i = 0; i < 8; i++)
            #pragma unroll
            for (int j = 0; j < 8; j++)
                acc[i][j] = fmaf(ve[i], kd[j], acc[i][j]);
    }

    unsigned short* Pb = P + (size_t)blk * 16384;
    #pragma unroll
    for (int i = 0; i < 8; i++) {
        const int e = te * 8 + i;
        uint4 w;
        w.x = f2bf(acc[i][0]) | (f2bf(acc[i][1]) << 16);
        w.y = f2bf(acc[i][2]) | (f2bf(acc[i][3]) << 16);
        w.z = f2bf(acc[i][4]) | (f2bf(acc[i][5]) << 16);
        w.w = f2bf(acc[i][6]) | (f2bf(acc[i][7]) << 16);
        *(uint4*)(Pb + e * 128 + td * 8) = w;   // 16 lanes x 16 B coalesced
    }
}

// ---------------- K2: reduce 64 partials -> Tt[b][e][d] * s -----------------
// grid 256 x 256 : one thread = 2 consecutive bf16 (one uint)
__global__ __launch_bounds__(256) void reduce_t(const unsigned short* __restrict__ P,
                                                const float* __restrict__ qk_sf,
                                                unsigned short* __restrict__ Tt) {
    const int u   = blockIdx.x * 256 + threadIdx.x;  // 0..65535
    const int b   = u >> 13;
    const int rem = u & 8191;                        // uint index within batch

    const unsigned short* Pb = P + (size_t)b * 64 * 16384 + rem * 2;
    float a0 = 0.f, a1 = 0.f;
    #pragma unroll 8
    for (int kc = 0; kc < 64; kc++) {
        unsigned int w = *(const unsigned int*)(Pb + (size_t)kc * 16384);
        a0 += __uint_as_float(w << 16);
        a1 += __uint_as_float(w & 0xffff0000u);
    }
    const float s = 1.0f / (sqrtf(128.0f) * qk_sf[0]);
    unsigned int o = f2bf(a0 * s) | (f2bf(a1 * s) << 16);
    *(unsigned int*)(Tt + (size_t)b * 16384 + rem * 2) = o;
}

// ---------------- K3: O = Q @ T  (MFMA bf16) --------------------------------
// grid = 512: blockIdx = b*64 + qc (32 q-rows per block)
__global__ __launch_bounds__(256) void qt_mfma(const float* __restrict__ Q,
                                               const unsigned short* __restrict__ Tt,
                                               float* __restrict__ O) {
    __shared__ unsigned short Ts[128 * 136];  // Tt[e][d], pad 136
    __shared__ unsigned short Qs[32 * 136];   // Q[q][d] bf16
    const int b   = blockIdx.x >> 6;
    const int q0  = (blockIdx.x & 63) * 32;
    const int tid = threadIdx.x;

    const uint4* Tg = (const uint4*)(Tt + (size_t)b * 16384);  // 2048 uint4
    #pragma unroll
    for (int i = 0; i < 8; i++) {
        int idx = tid + i * 256;
        int row = idx >> 4, c = idx & 15;
        *(uint4*)&Ts[row * 136 + c * 8] = Tg[idx];
    }
    const float4* Qg = (const float4*)(Q + ((size_t)b * SEQ + q0) * DIM); // 1024 float4
    #pragma unroll
    for (int i = 0; i < 4; i++) {
        int idx = tid + i * 256;
        int row = idx >> 5, c = idx & 31;
        float4 v = Qg[idx];
        uint2 w;
        w.x = f2bf(v.x) | (f2bf(v.y) << 16);
        w.y = f2bf(v.z) | (f2bf(v.w) << 16);
        *(uint2*)&Qs[row * 136 + c * 4] = w;
    }
    __syncthreads();

    const int wave = tid >> 6, lane = tid & 63;
    const int lm   = lane & 15, quad = lane >> 4;
    const int mrow = (wave & 1) * 16;        // q-tile within block
    const int n0   = (wave >> 1) * 64;       // e-range (4 n-tiles of 16)

    f32x4 acc[4] = {{0,0,0,0},{0,0,0,0},{0,0,0,0},{0,0,0,0}};
    #pragma unroll
    for (int ks = 0; ks < 4; ks++) {         // K = 128 in steps of 32
        short8 a = *(const short8*)&Qs[(mrow + lm) * 136 + ks * 32 + quad * 8];
        #pragma unroll
        for (int nt = 0; nt < 4; nt++) {
            short8 bb = *(const short8*)&Ts[(n0 + nt * 16 + lm) * 136 + ks * 32 + quad * 8];
            acc[nt] = __builtin_amdgcn_mfma_f32_16x16x32_bf16(a, bb, acc[nt], 0, 0, 0);
        }
    }

    float* Og = O + ((size_t)b * SEQ + q0) * DIM;
    #pragma unroll
    for (int nt = 0; nt < 4; nt++)
        #pragma unroll
        for (int r = 0; r < 4; r++) {
            const int row = mrow + quad * 4 + r;        // C/D: row = quad*4 + reg
            const int col = n0 + nt * 16 + lm;          //      col = lane&15
            Og[row * DIM + col] = acc[nt][r];
        }
}

extern "C" void kernel_launch(void* const* d_in, const int* in_sizes, int n_in,
                              void* d_out, int out_size, void* d_ws, size_t ws_size,
                              hipStream_t stream) {
    const float* qk_sf = (const float*)d_in[1];
    const float* Q = (const float*)d_in[2];
    const float* K = (const float*)d_in[3];
    const float* V = (const float*)d_in[4];
    float* O = (float*)d_out;

    unsigned short* P  = (unsigned short*)d_ws;                         // 512*16384*2B = 16 MB
    unsigned short* Tt = (unsigned short*)((char*)d_ws + (size_t)512 * 16384 * 2);

    vtk_partial<<<dim3(512), dim3(256), 0, stream>>>(K, V, P);
    reduce_t<<<dim3(256), dim3(256), 0, stream>>>(P, qk_sf, Tt);
    qt_mfma<<<dim3(BATCH * 64), dim3(256), 0, stream>>>(Q, Tt, O);
}

// Round 4
// 97.297 us; speedup vs baseline: 1.0265x; 1.0265x over previous
//
#include <hip/hip_runtime.h>

// O[b,q,e] = (Q·K^T)/(sqrt(128)*qk_sf) @ V  ==  Q @ (K^T V) * s   (no softmax)
// B=8, S=2048, D=128 fp32.
// K1: P[blk<256][e=128][d=128] bf16 partial of V^T K over 64 k-rows,
//     block=512 with in-block split-k (two 32-row halves, LDS-merged).
// K2: Tt[b][e][d] = s * sum_{kc<32} P  (bf16, scale folded; grid 256)
// K3: O = Q @ T via mfma_f32_16x16x32_bf16 (B-frag reads Tt[e][d] contiguously)

#define BATCH 8
#define SEQ 2048
#define DIM 128

typedef __attribute__((ext_vector_type(8))) short short8;
typedef __attribute__((ext_vector_type(4))) float f32x4;

__device__ __forceinline__ unsigned int f2bf(float f) {
    unsigned int u = __float_as_uint(f);
    u += 0x7fffu + ((u >> 16) & 1u);   // RNE
    return u >> 16;
}

// ---------------- K1: partial V^T K, split-k 8x8 tile -----------------------
// grid 256: blk = b*32 + kc (64 k-rows each); block 512 (8 waves/CU)
__global__ __launch_bounds__(512) void vtk_partial(const float* __restrict__ K,
                                                   const float* __restrict__ V,
                                                   unsigned short* __restrict__ P) {
    __shared__ float smem[2 * 64 * 128];       // 64 KB: Kc | Vc, reused for reduce
    float* Kc = smem;
    float* Vc = smem + 64 * 128;
    const int blk = blockIdx.x;
    const int b   = blk >> 5;
    const int kc  = blk & 31;
    const int tid = threadIdx.x;

    const float4* Kg = (const float4*)(K + ((size_t)b * SEQ + kc * 64) * DIM);
    const float4* Vg = (const float4*)(V + ((size_t)b * SEQ + kc * 64) * DIM);
    #pragma unroll
    for (int i = 0; i < 4; i++) {              // 2048 float4 each
        int idx = tid + i * 512;
        ((float4*)Kc)[idx] = Kg[idx];
        ((float4*)Vc)[idx] = Vg[idx];
    }
    __syncthreads();

    const int h  = tid >> 8;    // k-half: rows h*32 .. h*32+31
    const int t  = tid & 255;
    const int td = t & 15;      // d-octet
    const int te = t >> 4;      // e-octet

    float acc[8][8];
    #pragma unroll
    for (int i = 0; i < 8; i++)
        #pragma unroll
        for (int j = 0; j < 8; j++) acc[i][j] = 0.0f;

    const float* Kh = Kc + h * 32 * 128;
    const float* Vh = Vc + h * 32 * 128;
    #pragma unroll 4
    for (int k = 0; k < 32; k++) {
        const float4 k0 = *(const float4*)&Kh[k * 128 + td * 8];
        const float4 k1 = *(const float4*)&Kh[k * 128 + td * 8 + 4];
        const float4 v0 = *(const float4*)&Vh[k * 128 + te * 8];
        const float4 v1 = *(const float4*)&Vh[k * 128 + te * 8 + 4];
        const float kd[8] = {k0.x, k0.y, k0.z, k0.w, k1.x, k1.y, k1.z, k1.w};
        const float ve[8] = {v0.x, v0.y, v0.z, v0.w, v1.x, v1.y, v1.z, v1.w};
        #pragma unroll
        for (int i = 0; i < 8; i++)
            #pragma unroll
            for (int j = 0; j < 8; j++)
                acc[i][j] = fmaf(ve[i], kd[j], acc[i][j]);
    }
    __syncthreads();                            // staging reads done everywhere

    // half 1 dumps its 8x8 acc (16 float4) to LDS, [j4][t] layout (conflict-free)
    float4* red = (float4*)smem;                // 16 x 256 float4 = 64 KB
    if (h == 1) {
        #pragma unroll
        for (int i = 0; i < 8; i++) {
            *(float4*)&red[(i * 2 + 0) * 256 + t] =
                make_float4(acc[i][0], acc[i][1], acc[i][2], acc[i][3]);
            *(float4*)&red[(i * 2 + 1) * 256 + t] =
                make_float4(acc[i][4], acc[i][5], acc[i][6], acc[i][7]);
        }
    }
    __syncthreads();

    if (h == 0) {
        unsigned short* Pb = P + (size_t)blk * 16384;
        #pragma unroll
        for (int i = 0; i < 8; i++) {
            const float4 p0 = red[(i * 2 + 0) * 256 + t];
            const float4 p1 = red[(i * 2 + 1) * 256 + t];
            const float s0 = acc[i][0] + p0.x, s1 = acc[i][1] + p0.y;
            const float s2 = acc[i][2] + p0.z, s3 = acc[i][3] + p0.w;
            const float s4 = acc[i][4] + p1.x, s5 = acc[i][5] + p1.y;
            const float s6 = acc[i][6] + p1.z, s7 = acc[i][7] + p1.w;
            uint4 w;
            w.x = f2bf(s0) | (f2bf(s1) << 16);
            w.y = f2bf(s2) | (f2bf(s3) << 16);
            w.z = f2bf(s4) | (f2bf(s5) << 16);
            w.w = f2bf(s6) | (f2bf(s7) << 16);
            *(uint4*)(Pb + (te * 8 + i) * 128 + td * 8) = w;
        }
    }
}

// ---------------- K2: reduce 32 partials -> Tt[b][e][d] * s -----------------
// grid 256 x 256 : one thread = 2 consecutive bf16 (one uint)
__global__ __launch_bounds__(256) void reduce_t(const unsigned short* __restrict__ P,
                                                const float* __restrict__ qk_sf,
                                                unsigned short* __restrict__ Tt) {
    const int u   = blockIdx.x * 256 + threadIdx.x;  // 0..65535
    const int b   = u >> 13;
    const int rem = u & 8191;                        // uint index within batch

    const unsigned short* Pb = P + (size_t)b * 32 * 16384 + rem * 2;
    float a0 = 0.f, a1 = 0.f;
    #pragma unroll 8
    for (int kc = 0; kc < 32; kc++) {
        unsigned int w = *(const unsigned int*)(Pb + (size_t)kc * 16384);
        a0 += __uint_as_float(w << 16);
        a1 += __uint_as_float(w & 0xffff0000u);
    }
    const float s = 1.0f / (sqrtf(128.0f) * qk_sf[0]);
    unsigned int o = f2bf(a0 * s) | (f2bf(a1 * s) << 16);
    *(unsigned int*)(Tt + (size_t)b * 16384 + rem * 2) = o;
}

// ---------------- K3: O = Q @ T  (MFMA bf16) --------------------------------
// grid = 512: blockIdx = b*64 + qc (32 q-rows per block)
__global__ __launch_bounds__(256) void qt_mfma(const float* __restrict__ Q,
                                               const unsigned short* __restrict__ Tt,
                                               float* __restrict__ O) {
    __shared__ unsigned short Ts[128 * 136];  // Tt[e][d], pad 136
    __shared__ unsigned short Qs[32 * 136];   // Q[q][d] bf16
    const int b   = blockIdx.x >> 6;
    const int q0  = (blockIdx.x & 63) * 32;
    const int tid = threadIdx.x;

    const uint4* Tg = (const uint4*)(Tt + (size_t)b * 16384);  // 2048 uint4
    #pragma unroll
    for (int i = 0; i < 8; i++) {
        int idx = tid + i * 256;
        int row = idx >> 4, c = idx & 15;
        *(uint4*)&Ts[row * 136 + c * 8] = Tg[idx];
    }
    const float4* Qg = (const float4*)(Q + ((size_t)b * SEQ + q0) * DIM); // 1024 float4
    #pragma unroll
    for (int i = 0; i < 4; i++) {
        int idx = tid + i * 256;
        int row = idx >> 5, c = idx & 31;
        float4 v = Qg[idx];
        uint2 w;
        w.x = f2bf(v.x) | (f2bf(v.y) << 16);
        w.y = f2bf(v.z) | (f2bf(v.w) << 16);
        *(uint2*)&Qs[row * 136 + c * 4] = w;
    }
    __syncthreads();

    const int wave = tid >> 6, lane = tid & 63;
    const int lm   = lane & 15, quad = lane >> 4;
    const int mrow = (wave & 1) * 16;        // q-tile within block
    const int n0   = (wave >> 1) * 64;       // e-range (4 n-tiles of 16)

    f32x4 acc[4] = {{0,0,0,0},{0,0,0,0},{0,0,0,0},{0,0,0,0}};
    #pragma unroll
    for (int ks = 0; ks < 4; ks++) {         // K = 128 in steps of 32
        short8 a = *(const short8*)&Qs[(mrow + lm) * 136 + ks * 32 + quad * 8];
        #pragma unroll
        for (int nt = 0; nt < 4; nt++) {
            short8 bb = *(const short8*)&Ts[(n0 + nt * 16 + lm) * 136 + ks * 32 + quad * 8];
            acc[nt] = __builtin_amdgcn_mfma_f32_16x16x32_bf16(a, bb, acc[nt], 0, 0, 0);
        }
    }

    float* Og = O + ((size_t)b * SEQ + q0) * DIM;
    #pragma unroll
    for (int nt = 0; nt < 4; nt++)
        #pragma unroll
        for (int r = 0; r < 4; r++) {
            const int row = mrow + quad * 4 + r;        // C/D: row = quad*4 + reg
            const int col = n0 + nt * 16 + lm;          //      col = lane&15
            Og[row * DIM + col] = acc[nt][r];
        }
}

extern "C" void kernel_launch(void* const* d_in, const int* in_sizes, int n_in,
                              void* d_out, int out_size, void* d_ws, size_t ws_size,
                              hipStream_t stream) {
    const float* qk_sf = (const float*)d_in[1];
    const float* Q = (const float*)d_in[2];
    const float* K = (const float*)d_in[3];
    const float* V = (const float*)d_in[4];
    float* O = (float*)d_out;

    unsigned short* P  = (unsigned short*)d_ws;                         // 256*16384*2B = 8 MB
    unsigned short* Tt = (unsigned short*)((char*)d_ws + (size_t)256 * 16384 * 2);

    vtk_partial<<<dim3(256), dim3(512), 0, stream>>>(K, V, P);
    reduce_t<<<dim3(256), dim3(256), 0, stream>>>(P, qk_sf, Tt);
    qt_mfma<<<dim3(BATCH * 64), dim3(256), 0, stream>>>(Q, Tt, O);
}